// Round 18
// baseline (182.808 us; speedup 1.0000x reference)
//
#include <hip/hip_runtime.h>

#define B_NODES 20000
#define N1_NODES 80000
#define NTOT 100000            // B + N1
#define E_EDGES 800000
#define CIN 256
#define COUT 256
#define NUM_D 32
#define NB 8                   // CIN / NUM_D
#define NUM_M 4096
#define NUM_N 200000
#define NPART 2048             // scalar partial buckets
#define CAP 40                 // bucket capacity per node
#define NXCVT 313              // x->bf16 conversion blocks
#define NZB 100                // cnt/scalpart zeroing blocks
#define NG1 1563               // ceil(NTOT/64) gemm1 blocks (512 threads each)
#define NG2 626                // 313 M-tiles x 2 N-halves
#define EPB1 512               // edges per gemm1 block (1563*512 >= 800000)

typedef __attribute__((ext_vector_type(8))) short short8;
typedef __attribute__((ext_vector_type(4))) short s16x4;
typedef __attribute__((ext_vector_type(8))) unsigned short ushort8;
typedef __attribute__((ext_vector_type(4))) float f32x4;
typedef __attribute__((ext_vector_type(4))) int i32x4;

// f32 -> bf16 round-to-nearest-even
__device__ inline unsigned short f2bf(float f) {
    unsigned int u = __float_as_uint(f);
    u += 0x7FFFu + ((u >> 16) & 1u);
    return (unsigned short)(u >> 16);
}
__device__ inline float bf2f(unsigned short u) {
    return __uint_as_float((unsigned int)u << 16);
}

__device__ inline short8 pack2(float4 a, float4 b) {
    short8 r;
    r[0] = (short)f2bf(a.x); r[1] = (short)f2bf(a.y);
    r[2] = (short)f2bf(a.z); r[3] = (short)f2bf(a.w);
    r[4] = (short)f2bf(b.x); r[5] = (short)f2bf(b.y);
    r[6] = (short)f2bf(b.z); r[7] = (short)f2bf(b.w);
    return r;
}
__device__ inline s16x4 pack1(float4 a) {
    s16x4 r;
    r[0] = (short)f2bf(a.x); r[1] = (short)f2bf(a.y);
    r[2] = (short)f2bf(a.z); r[3] = (short)f2bf(a.w);
    return r;
}

// ---------------------------------------------------------------------------
// prepW: [0,48): weight transpose+cvt
//        [48, 48+NXCVT): xb = bf16(x)
//        [48+NXCVT, 48+NXCVT+NZB): zero cnt+scalpart (int4 grid-stride)
// ---------------------------------------------------------------------------
__global__ __launch_bounds__(256) void prepw_kernel(
    const float* __restrict__ Wc, const float* __restrict__ Wt,
    const float* __restrict__ Ws, short* __restrict__ WcT,
    short* __restrict__ WoT, const float* __restrict__ x,
    unsigned short* __restrict__ xb, int* __restrict__ cnt)
{
    __shared__ float Ls[64][65];
    if (blockIdx.x < 48) {
        const int z   = blockIdx.x >> 4;
        const int rem = blockIdx.x & 15;
        const int kx  = rem & 3, ny = rem >> 2;
        const float* src = (z == 0) ? Wc : ((z == 1) ? Wt : Ws);
        short* dst = (z == 0) ? WcT : WoT;
        const int dstStride = (z == 0) ? 256 : 512;
        const int colOff = (z == 2) ? 256 : 0;

        const int k0 = kx * 64, n0 = ny * 64;
        const int tid = threadIdx.x;
        #pragma unroll
        for (int lp = 0; lp < 16; ++lp) {
            int idx = tid + lp * 256;
            int rr = idx >> 6, cc = idx & 63;
            Ls[rr][cc] = src[(size_t)(k0 + rr) * 256 + n0 + cc];
        }
        __syncthreads();
        #pragma unroll
        for (int lp = 0; lp < 16; ++lp) {
            int idx = tid + lp * 256;
            int rr = idx >> 6, cc = idx & 63;
            dst[(size_t)(n0 + rr) * dstStride + colOff + k0 + cc] =
                (short)f2bf(Ls[cc][rr]);
        }
    } else if (blockIdx.x < 48 + NXCVT) {
        const int base = (blockIdx.x - 48) * 256 + threadIdx.x;
        const int total8 = B_NODES * CIN / 8;        // 640000
        for (int g = base; g < total8; g += NXCVT * 256) {
            const float4* src = (const float4*)(x + (size_t)g * 8);
            *(short8*)(xb + (size_t)g * 8) = pack2(src[0], src[1]);
        }
    } else {
        // zero cnt (NTOT) + scalpart (NPART)
        const int base = (blockIdx.x - 48 - NXCVT) * 256 + threadIdx.x;
        const int total4 = (NTOT + NPART) / 4;       // 25512
        i32x4 z = {0, 0, 0, 0};
        for (int g = base; g < total4; g += NZB * 256)
            ((i32x4*)cnt)[g] = z;
    }
}

// ---------------------------------------------------------------------------
// GEMM 1 (MFMA bf16, 512 threads, BK=64 double sub-stage) + scatter tail:
//   64M x 256N tile, 8 waves x 32 cols, LDS 46KB (3 blocks/CU)
//   4 barrier pairs (vs 8), 16 MFMA/wave per pair
//   cind loads hoisted; A rows<B from xb; rows>=B codebook gather
//   tail: 1 edge per thread -> bucket scatter
// ---------------------------------------------------------------------------
__global__ __launch_bounds__(512) void gemm1_scat_kernel(
    const unsigned short* __restrict__ xb, const int* __restrict__ fo,
    const int* __restrict__ cind, const float* __restrict__ cb,
    const short* __restrict__ WcT, unsigned short* __restrict__ xwb,
    const int* __restrict__ ei, const float* __restrict__ ew,
    int* __restrict__ cnt, int2* __restrict__ esw)
{
    __shared__ short As[64 * 72];    // [row][64k + pad8]
    __shared__ short Bs[256 * 72];

    const int tid  = threadIdx.x;
    const int w    = tid >> 6, l = tid & 63;
    const int row0 = blockIdx.x * 64;
    const int r    = tid >> 3, q = tid & 7;      // A staging: row, k-eighth of 32
    const int bcol = tid >> 1, bq = tid & 1;     // B staging: col, 16-k half of 32
    const int grow = row0 + r;
    const int g16  = (l >> 4) * 8;

    const bool isx  = grow < B_NODES;
    const bool iscb = !isx && grow < NTOT;
    const int fi = iscb ? fo[grow - B_NODES] : 0;

    // hoist all 8 cind loads (independent -> full MLP)
    int cidx[8];
    #pragma unroll
    for (int ks = 0; ks < 8; ++ks)
        cidx[ks] = iscb ? cind[ks * NUM_N + fi] : 0;

    f32x4 acc[4][2] = {};

    for (int kso = 0; kso < 4; ++kso) {
        // ---- stage 64 k-columns (two 32-k halves) ----
        #pragma unroll
        for (int h = 0; h < 2; ++h) {
            const int ks = kso * 2 + h;
            const int k0 = ks * 32;
            s16x4 sv = {0, 0, 0, 0};
            if (isx) {
                sv = *(const s16x4*)(xb + (size_t)grow * CIN + k0 + q * 4);
            } else if (iscb) {
                float4 f = *(const float4*)(cb +
                    ((size_t)(ks * NUM_M + cidx[ks])) * (2 * NUM_D) + q * 4);
                sv = pack1(f);
            }
            *(s16x4*)&As[r * 72 + h * 32 + q * 4] = sv;

            const short8* wp = (const short8*)(WcT + (size_t)bcol * 256 + k0 + bq * 16);
            short8* bd = (short8*)&Bs[bcol * 72 + h * 32 + bq * 16];
            bd[0] = wp[0]; bd[1] = wp[1];
        }
        __syncthreads();

        // ---- 16 MFMA per wave (two 32-k halves) ----
        #pragma unroll
        for (int h = 0; h < 2; ++h) {
            short8 av[4], bv[2];
            #pragma unroll
            for (int m = 0; m < 4; ++m)
                av[m] = *(const short8*)&As[((l & 15) + 16 * m) * 72 + h * 32 + g16];
            #pragma unroll
            for (int n = 0; n < 2; ++n)
                bv[n] = *(const short8*)&Bs[((l & 15) + 16 * n + w * 32) * 72 + h * 32 + g16];
            #pragma unroll
            for (int m = 0; m < 4; ++m)
                #pragma unroll
                for (int n = 0; n < 2; ++n)
                    acc[m][n] = __builtin_amdgcn_mfma_f32_16x16x32_bf16(
                        av[m], bv[n], acc[m][n], 0, 0, 0);
        }
        __syncthreads();
    }

    #pragma unroll
    for (int m = 0; m < 4; ++m) {
        int rbase = row0 + 16 * m + (l >> 4) * 4;
        #pragma unroll
        for (int n = 0; n < 2; ++n) {
            int col = w * 32 + 16 * n + (l & 15);
            #pragma unroll
            for (int j = 0; j < 4; ++j) {
                int rr = rbase + j;
                if (rr < NTOT)
                    xwb[(size_t)rr * COUT + col] = f2bf(acc[m][n][j]);
            }
        }
    }

    // --- scatter tail: 1 edge per thread ---
    int e = blockIdx.x * EPB1 + tid;
    if (e < E_EDGES) {
        int dst = ei[E_EDGES + e];
        int pos = atomicAdd(&cnt[dst], 1);
        esw[(size_t)dst * CAP + pos] = make_int2(ei[e], __float_as_int(ew[e]));
    }
}

// ---------------------------------------------------------------------------
// gather-accumulate: one wave per destination node (+ fused info_backward)
// ceil-8 masked loop: every edge gets 4-deep MLP
// ---------------------------------------------------------------------------
__global__ __launch_bounds__(256) void gather_accum_kernel(
    const unsigned short* __restrict__ xwb, const int2* __restrict__ esw,
    const int* __restrict__ cnt, const float* __restrict__ b_conv,
    const int* __restrict__ fo, const int* __restrict__ cind,
    const float* __restrict__ cb,
    unsigned short* __restrict__ xoutb, float* __restrict__ scalpart)
{
    const int wid  = threadIdx.x >> 6;
    const int lane = threadIdx.x & 63;
    const int node = blockIdx.x * 4 + wid;
    if (node >= NTOT) return;

    const int half = lane >> 5;     // 0: even edge, 1: odd edge
    const int l32  = lane & 31;
    const int c0   = l32 * 8;       // 8 columns per lane

    float acc[8];
    if (half == 0) {
        float4 b0 = *(const float4*)(b_conv + c0);
        float4 b1 = *(const float4*)(b_conv + c0 + 4);
        acc[0] = b0.x; acc[1] = b0.y; acc[2] = b0.z; acc[3] = b0.w;
        acc[4] = b1.x; acc[5] = b1.y; acc[6] = b1.z; acc[7] = b1.w;
    } else {
        #pragma unroll
        for (int k = 0; k < 8; ++k) acc[k] = 0.0f;
    }

    const int s = node * CAP;
    const int e = s + cnt[node];
    for (int j = s; j < e; j += 8) {
        int2  p[4];
        float w[4];
        #pragma unroll
        for (int t = 0; t < 4; ++t) {
            int idx = j + 2 * t + half;
            bool valid = idx < e;
            p[t] = esw[valid ? idx : s];
            w[t] = valid ? __int_as_float(p[t].y) : 0.0f;
        }
        ushort8 u[4];
        #pragma unroll
        for (int t = 0; t < 4; ++t)
            u[t] = *(const ushort8*)(xwb + (size_t)p[t].x * CIN + c0);
        #pragma unroll
        for (int t = 0; t < 4; ++t) {
            #pragma unroll
            for (int k = 0; k < 8; ++k) acc[k] += bf2f(u[t][k]) * w[t];
        }
    }

    // fold odd-edge half into even half
    #pragma unroll
    for (int k = 0; k < 8; ++k) acc[k] += __shfl_xor(acc[k], 32, 64);

    if (node < B_NODES) {
        if (half == 0) {
            ushort8 o;
            #pragma unroll
            for (int k = 0; k < 8; ++k) o[k] = f2bf(acc[k]);
            *(ushort8*)(xoutb + (size_t)node * CIN + c0) = o;
        }
    } else {
        float v = 0.0f;
        if (half == 0) {
            int i = node - B_NODES;
            int b = l32 >> 2;              // (l32*8)/32
            int d = (l32 & 3) * 8;
            int cidx = cind[b * NUM_N + fo[i]];
            const float* gp = cb + ((size_t)(b * NUM_M + cidx)) * (2 * NUM_D)
                              + NUM_D + d;
            float4 g0 = *(const float4*)gp;
            float4 g1 = *(const float4*)(gp + 4);
            v = acc[0] * g0.x + acc[1] * g0.y + acc[2] * g0.z + acc[3] * g0.w
              + acc[4] * g1.x + acc[5] * g1.y + acc[6] * g1.z + acc[7] * g1.w;
        }
        #pragma unroll
        for (int off = 32; off > 0; off >>= 1) v += __shfl_down(v, off, 64);
        if (lane == 0)
            atomicAdd(&scalpart[node & (NPART - 1)], v);
    }
}

// ---------------------------------------------------------------------------
// FUSED: GEMM2 out = xoutb[:B]@W_t + xb@W_skip + biases, N-split (128 cols)
//        + finalize scalar (block NG2).  BK=64 double sub-stage.
// ---------------------------------------------------------------------------
__global__ __launch_bounds__(256) void gemm2_fin_kernel(
    const unsigned short* __restrict__ xoutb, const unsigned short* __restrict__ xb,
    const short* __restrict__ WoT,
    const float* __restrict__ bt, const float* __restrict__ bskip,
    const float* __restrict__ scalpart, const float* __restrict__ wur,
    float* __restrict__ out)
{
    if (blockIdx.x == NG2) {
        __shared__ float wsum[4];
        float v = 0.0f;
        for (int i = threadIdx.x; i < NPART; i += 256) v += scalpart[i];
        #pragma unroll
        for (int off = 32; off > 0; off >>= 1) v += __shfl_down(v, off, 64);
        if ((threadIdx.x & 63) == 0) wsum[threadIdx.x >> 6] = v;
        __syncthreads();
        if (threadIdx.x == 0)
            out[(size_t)B_NODES * COUT] =
                (wsum[0] + wsum[1] + wsum[2] + wsum[3]) * wur[0];
        return;
    }

    __shared__ short As[2][64 * 40];
    __shared__ short Bs[2][128 * 40];
    __shared__ float bsum[128];

    const int tid  = threadIdx.x;
    const int w    = tid >> 6, l = tid & 63;
    const int row0 = (blockIdx.x >> 1) * 64;
    const int colbase = (blockIdx.x & 1) * 128;
    const int r    = tid >> 2, q = tid & 3;      // A staging
    const int bc_  = tid >> 1, bq = tid & 1;     // B staging: col, 16-k half
    const int grow = row0 + r;
    const int g16  = (l >> 4) * 8;

    if (tid < 128) bsum[tid] = bt[colbase + tid] + bskip[colbase + tid];

    f32x4 acc[4][2] = {};

    for (int kso = 0; kso < 8; ++kso) {
        #pragma unroll
        for (int h = 0; h < 2; ++h) {
            const int ks = kso * 2 + h;
            const int k0 = ks * 32;
            short8 sv = {0,0,0,0,0,0,0,0};
            if (grow < B_NODES) {
                const unsigned short* base = (ks < 8)
                    ? (xoutb + (size_t)grow * CIN + k0)
                    : (xb    + (size_t)grow * CIN + (k0 - 256));
                sv = *(const short8*)(base + q * 8);
            }
            *(short8*)&As[h][r * 40 + q * 8] = sv;

            const short8* wp = (const short8*)(WoT +
                (size_t)(colbase + bc_) * 512 + k0 + bq * 16);
            short8* bd = (short8*)&Bs[h][bc_ * 40 + bq * 16];
            bd[0] = wp[0]; bd[1] = wp[1];
        }
        __syncthreads();

        #pragma unroll
        for (int h = 0; h < 2; ++h) {
            short8 av[4], bv[2];
            #pragma unroll
            for (int m = 0; m < 4; ++m)
                av[m] = *(const short8*)&As[h][((l & 15) + 16 * m) * 40 + g16];
            #pragma unroll
            for (int n = 0; n < 2; ++n)
                bv[n] = *(const short8*)&Bs[h][((l & 15) + 16 * n + w * 32) * 40 + g16];
            #pragma unroll
            for (int m = 0; m < 4; ++m)
                #pragma unroll
                for (int n = 0; n < 2; ++n)
                    acc[m][n] = __builtin_amdgcn_mfma_f32_16x16x32_bf16(
                        av[m], bv[n], acc[m][n], 0, 0, 0);
        }
        __syncthreads();
    }

    #pragma unroll
    for (int m = 0; m < 4; ++m) {
        int rbase = row0 + 16 * m + (l >> 4) * 4;
        #pragma unroll
        for (int n = 0; n < 2; ++n) {
            int lcol = w * 32 + 16 * n + (l & 15);
            int col  = colbase + lcol;
            float bc = bsum[lcol];
            #pragma unroll
            for (int j = 0; j < 4; ++j) {
                int rr = rbase + j;
                if (rr < B_NODES)
                    out[(size_t)rr * COUT + col] = acc[m][n][j] + bc;
            }
        }
    }
}

// ---------------------------------------------------------------------------
extern "C" void kernel_launch(void* const* d_in, const int* in_sizes, int n_in,
                              void* d_out, int out_size, void* d_ws, size_t ws_size,
                              hipStream_t stream)
{
    const float* x       = (const float*)d_in[0];
    const float* ew      = (const float*)d_in[1];
    const float* cb      = (const float*)d_in[2];
    const float* W_conv  = (const float*)d_in[3];
    const float* b_conv  = (const float*)d_in[4];
    const float* W_t     = (const float*)d_in[5];
    const float* b_t     = (const float*)d_in[6];
    const float* W_skip  = (const float*)d_in[7];
    const float* b_skip  = (const float*)d_in[8];
    const float* wur     = (const float*)d_in[9];
    const int*   cind    = (const int*)d_in[10];
    const int*   fo      = (const int*)d_in[11];
    const int*   ei      = (const int*)d_in[12];

    float* out = (float*)d_out;

    // workspace layout (cnt & scalpart adjacent, zeroed by prepw)
    unsigned short* xwb   = (unsigned short*)d_ws;              // NTOT*CIN bf16 (51.2MB)
    unsigned short* xoutb = xwb + (size_t)NTOT * CIN;           // B*CIN bf16 (10.2MB)
    unsigned short* xb    = xoutb + (size_t)B_NODES * CIN;      // B*CIN bf16 (10.2MB)
    short* WcT      = (short*)(xb + (size_t)B_NODES * CIN);     // 256*256 bf16
    short* WoT      = WcT + 256 * 256;                          // 256*512 bf16
    int2*  esw      = (int2*)(WoT + 256 * 512);                 // NTOT*CAP (32MB)
    int*   cnt      = (int*)(esw + (size_t)NTOT * CAP);         // NTOT
    float* scalpart = (float*)(cnt + NTOT);                     // NPART

    // weight transpose + x->bf16 + zero cnt/scalpart (one launch)
    prepw_kernel<<<48 + NXCVT + NZB, 256, 0, stream>>>(
        W_conv, W_t, W_skip, WcT, WoT, x, xb, cnt);

    // GEMM1 (512-thread, BK=64) with per-block edge-scatter tail
    gemm1_scat_kernel<<<NG1, 512, 0, stream>>>(
        xb, fo, cind, cb, WcT, xwb, ei, ew, cnt, esw);

    // per-destination gather + accumulate (+ fused info_backward)
    gather_accum_kernel<<<NTOT / 4, 256, 0, stream>>>(
        xwb, esw, cnt, b_conv, fo, cind, cb, xoutb, scalpart);

    // GEMM2 (N-split, 626 blocks) + finalize
    gemm2_fin_kernel<<<NG2 + 1, 256, 0, stream>>>(
        xoutb, xb, WoT, b_t, b_skip, scalpart, wur, out);
}

// Round 19
// 171.346 us; speedup vs baseline: 1.0669x; 1.0669x over previous
//
#include <hip/hip_runtime.h>

#define B_NODES 20000
#define N1_NODES 80000
#define NTOT 100000            // B + N1
#define E_EDGES 800000
#define CIN 256
#define COUT 256
#define NUM_D 32
#define NB 8                   // CIN / NUM_D
#define NUM_M 4096
#define NUM_N 200000
#define NPART 2048             // scalar partial buckets
#define CAP 40                 // bucket capacity per node
#define NXCVT 313              // x->bf16 conversion blocks
#define NZB 100                // cnt/scalpart zeroing blocks
#define NG1 1563               // ceil(NTOT/64) gemm1 blocks (512 threads each)
#define NG2 626                // 313 M-tiles x 2 N-halves
#define EPB1 512               // edges per gemm1 block (1563*512 >= 800000)

typedef __attribute__((ext_vector_type(8))) short short8;
typedef __attribute__((ext_vector_type(4))) short s16x4;
typedef __attribute__((ext_vector_type(8))) unsigned short ushort8;
typedef __attribute__((ext_vector_type(4))) float f32x4;
typedef __attribute__((ext_vector_type(4))) int i32x4;

// f32 -> bf16 round-to-nearest-even
__device__ inline unsigned short f2bf(float f) {
    unsigned int u = __float_as_uint(f);
    u += 0x7FFFu + ((u >> 16) & 1u);
    return (unsigned short)(u >> 16);
}
__device__ inline float bf2f(unsigned short u) {
    return __uint_as_float((unsigned int)u << 16);
}

__device__ inline short8 pack2(float4 a, float4 b) {
    short8 r;
    r[0] = (short)f2bf(a.x); r[1] = (short)f2bf(a.y);
    r[2] = (short)f2bf(a.z); r[3] = (short)f2bf(a.w);
    r[4] = (short)f2bf(b.x); r[5] = (short)f2bf(b.y);
    r[6] = (short)f2bf(b.z); r[7] = (short)f2bf(b.w);
    return r;
}
__device__ inline s16x4 pack1(float4 a) {
    s16x4 r;
    r[0] = (short)f2bf(a.x); r[1] = (short)f2bf(a.y);
    r[2] = (short)f2bf(a.z); r[3] = (short)f2bf(a.w);
    return r;
}

// ---------------------------------------------------------------------------
// prepW: [0,48): weight transpose+cvt
//        [48, 48+NXCVT): xb = bf16(x)
//        [48+NXCVT, 48+NXCVT+NZB): zero cnt+scalpart (int4 grid-stride)
// ---------------------------------------------------------------------------
__global__ __launch_bounds__(256) void prepw_kernel(
    const float* __restrict__ Wc, const float* __restrict__ Wt,
    const float* __restrict__ Ws, short* __restrict__ WcT,
    short* __restrict__ WoT, const float* __restrict__ x,
    unsigned short* __restrict__ xb, int* __restrict__ cnt)
{
    __shared__ float Ls[64][65];
    if (blockIdx.x < 48) {
        const int z   = blockIdx.x >> 4;
        const int rem = blockIdx.x & 15;
        const int kx  = rem & 3, ny = rem >> 2;
        const float* src = (z == 0) ? Wc : ((z == 1) ? Wt : Ws);
        short* dst = (z == 0) ? WcT : WoT;
        const int dstStride = (z == 0) ? 256 : 512;
        const int colOff = (z == 2) ? 256 : 0;

        const int k0 = kx * 64, n0 = ny * 64;
        const int tid = threadIdx.x;
        #pragma unroll
        for (int lp = 0; lp < 16; ++lp) {
            int idx = tid + lp * 256;
            int rr = idx >> 6, cc = idx & 63;
            Ls[rr][cc] = src[(size_t)(k0 + rr) * 256 + n0 + cc];
        }
        __syncthreads();
        #pragma unroll
        for (int lp = 0; lp < 16; ++lp) {
            int idx = tid + lp * 256;
            int rr = idx >> 6, cc = idx & 63;
            dst[(size_t)(n0 + rr) * dstStride + colOff + k0 + cc] =
                (short)f2bf(Ls[cc][rr]);
        }
    } else if (blockIdx.x < 48 + NXCVT) {
        const int base = (blockIdx.x - 48) * 256 + threadIdx.x;
        const int total8 = B_NODES * CIN / 8;        // 640000
        for (int g = base; g < total8; g += NXCVT * 256) {
            const float4* src = (const float4*)(x + (size_t)g * 8);
            *(short8*)(xb + (size_t)g * 8) = pack2(src[0], src[1]);
        }
    } else {
        // zero cnt (NTOT) + scalpart (NPART)
        const int base = (blockIdx.x - 48 - NXCVT) * 256 + threadIdx.x;
        const int total4 = (NTOT + NPART) / 4;       // 25512
        i32x4 z = {0, 0, 0, 0};
        for (int g = base; g < total4; g += NZB * 256)
            ((i32x4*)cnt)[g] = z;
    }
}

// ---------------------------------------------------------------------------
// GEMM 1 (MFMA bf16, 512 threads, BK=32) + scatter tail:
//   64M x 256N tile, 8 waves x 32 cols, LDS 25.6KB (4 blocks/CU ceiling)
//   Tile permutation vt = bid*523 mod 1563 interleaves cheap x-row tiles
//   with slow codebook-gather tiles across dispatch order (load balance).
//   cind loads hoisted; tail: 1 edge per thread -> bucket scatter
// ---------------------------------------------------------------------------
__global__ __launch_bounds__(512) void gemm1_scat_kernel(
    const unsigned short* __restrict__ xb, const int* __restrict__ fo,
    const int* __restrict__ cind, const float* __restrict__ cb,
    const short* __restrict__ WcT, unsigned short* __restrict__ xwb,
    const int* __restrict__ ei, const float* __restrict__ ew,
    int* __restrict__ cnt, int2* __restrict__ esw)
{
    __shared__ short As[64 * 40];
    __shared__ short Bs[256 * 40];

    const int tid  = threadIdx.x;
    const int w    = tid >> 6, l = tid & 63;
    const int vt   = (int)(((long)blockIdx.x * 523) % NG1);   // bijective mix
    const int row0 = vt * 64;
    const int r    = tid >> 3, q = tid & 7;      // A staging: row, k-eighth
    const int bcol = tid >> 1, bq = tid & 1;     // B staging: col, 16-k half
    const int grow = row0 + r;
    const int g16  = (l >> 4) * 8;

    const bool isx  = grow < B_NODES;
    const bool iscb = !isx && grow < NTOT;
    const int fi = iscb ? fo[grow - B_NODES] : 0;

    // hoist all 8 cind loads (independent -> full MLP)
    int cidx[8];
    #pragma unroll
    for (int ks = 0; ks < 8; ++ks)
        cidx[ks] = iscb ? cind[ks * NUM_N + fi] : 0;

    f32x4 acc[4][2] = {};

    for (int ks = 0; ks < 8; ++ks) {
        const int k0 = ks * 32;
        // --- stage A: 64 x 32, s16x4 (8B) per thread ---
        s16x4 sv = {0, 0, 0, 0};
        if (isx) {
            sv = *(const s16x4*)(xb + (size_t)grow * CIN + k0 + q * 4);
        } else if (iscb) {
            float4 f = *(const float4*)(cb +
                ((size_t)(ks * NUM_M + cidx[ks])) * (2 * NUM_D) + q * 4);
            sv = pack1(f);
        }
        *(s16x4*)&As[r * 40 + q * 4] = sv;

        // --- stage B: 256 x 32, 2x short8 (32B) per thread ---
        {
            const short8* wp = (const short8*)(WcT + (size_t)bcol * 256 + k0 + bq * 16);
            short8* bd = (short8*)&Bs[bcol * 40 + bq * 16];
            bd[0] = wp[0]; bd[1] = wp[1];
        }
        __syncthreads();

        short8 av[4], bv[2];
        #pragma unroll
        for (int m = 0; m < 4; ++m)
            av[m] = *(const short8*)&As[((l & 15) + 16 * m) * 40 + g16];
        #pragma unroll
        for (int n = 0; n < 2; ++n)
            bv[n] = *(const short8*)&Bs[((l & 15) + 16 * n + w * 32) * 40 + g16];
        #pragma unroll
        for (int m = 0; m < 4; ++m)
            #pragma unroll
            for (int n = 0; n < 2; ++n)
                acc[m][n] = __builtin_amdgcn_mfma_f32_16x16x32_bf16(
                    av[m], bv[n], acc[m][n], 0, 0, 0);
        __syncthreads();
    }

    #pragma unroll
    for (int m = 0; m < 4; ++m) {
        int rbase = row0 + 16 * m + (l >> 4) * 4;
        #pragma unroll
        for (int n = 0; n < 2; ++n) {
            int col = w * 32 + 16 * n + (l & 15);
            #pragma unroll
            for (int j = 0; j < 4; ++j) {
                int rr = rbase + j;
                if (rr < NTOT)
                    xwb[(size_t)rr * COUT + col] = f2bf(acc[m][n][j]);
            }
        }
    }

    // --- scatter tail: 1 edge per thread ---
    int e = blockIdx.x * EPB1 + tid;
    if (e < E_EDGES) {
        int dst = ei[E_EDGES + e];
        int pos = atomicAdd(&cnt[dst], 1);
        esw[(size_t)dst * CAP + pos] = make_int2(ei[e], __float_as_int(ew[e]));
    }
}

// ---------------------------------------------------------------------------
// gather-accumulate: one wave per destination node (+ fused info_backward)
// ceil-8 masked loop: every edge gets 4-deep MLP
// ---------------------------------------------------------------------------
__global__ __launch_bounds__(256) void gather_accum_kernel(
    const unsigned short* __restrict__ xwb, const int2* __restrict__ esw,
    const int* __restrict__ cnt, const float* __restrict__ b_conv,
    const int* __restrict__ fo, const int* __restrict__ cind,
    const float* __restrict__ cb,
    unsigned short* __restrict__ xoutb, float* __restrict__ scalpart)
{
    const int wid  = threadIdx.x >> 6;
    const int lane = threadIdx.x & 63;
    const int node = blockIdx.x * 4 + wid;
    if (node >= NTOT) return;

    const int half = lane >> 5;     // 0: even edge, 1: odd edge
    const int l32  = lane & 31;
    const int c0   = l32 * 8;       // 8 columns per lane

    float acc[8];
    if (half == 0) {
        float4 b0 = *(const float4*)(b_conv + c0);
        float4 b1 = *(const float4*)(b_conv + c0 + 4);
        acc[0] = b0.x; acc[1] = b0.y; acc[2] = b0.z; acc[3] = b0.w;
        acc[4] = b1.x; acc[5] = b1.y; acc[6] = b1.z; acc[7] = b1.w;
    } else {
        #pragma unroll
        for (int k = 0; k < 8; ++k) acc[k] = 0.0f;
    }

    const int s = node * CAP;
    const int e = s + cnt[node];
    for (int j = s; j < e; j += 8) {
        int2  p[4];
        float w[4];
        #pragma unroll
        for (int t = 0; t < 4; ++t) {
            int idx = j + 2 * t + half;
            bool valid = idx < e;
            p[t] = esw[valid ? idx : s];
            w[t] = valid ? __int_as_float(p[t].y) : 0.0f;
        }
        ushort8 u[4];
        #pragma unroll
        for (int t = 0; t < 4; ++t)
            u[t] = *(const ushort8*)(xwb + (size_t)p[t].x * CIN + c0);
        #pragma unroll
        for (int t = 0; t < 4; ++t) {
            #pragma unroll
            for (int k = 0; k < 8; ++k) acc[k] += bf2f(u[t][k]) * w[t];
        }
    }

    // fold odd-edge half into even half
    #pragma unroll
    for (int k = 0; k < 8; ++k) acc[k] += __shfl_xor(acc[k], 32, 64);

    if (node < B_NODES) {
        if (half == 0) {
            ushort8 o;
            #pragma unroll
            for (int k = 0; k < 8; ++k) o[k] = f2bf(acc[k]);
            *(ushort8*)(xoutb + (size_t)node * CIN + c0) = o;
        }
    } else {
        float v = 0.0f;
        if (half == 0) {
            int i = node - B_NODES;
            int b = l32 >> 2;              // (l32*8)/32
            int d = (l32 & 3) * 8;
            int cidx = cind[b * NUM_N + fo[i]];
            const float* gp = cb + ((size_t)(b * NUM_M + cidx)) * (2 * NUM_D)
                              + NUM_D + d;
            float4 g0 = *(const float4*)gp;
            float4 g1 = *(const float4*)(gp + 4);
            v = acc[0] * g0.x + acc[1] * g0.y + acc[2] * g0.z + acc[3] * g0.w
              + acc[4] * g1.x + acc[5] * g1.y + acc[6] * g1.z + acc[7] * g1.w;
        }
        #pragma unroll
        for (int off = 32; off > 0; off >>= 1) v += __shfl_down(v, off, 64);
        if (lane == 0)
            atomicAdd(&scalpart[node & (NPART - 1)], v);
    }
}

// ---------------------------------------------------------------------------
// FUSED: GEMM2 out = xoutb[:B]@W_t + xb@W_skip + biases, N-split (128 cols)
//        + finalize scalar (block NG2).  BK=64 double sub-stage.
// ---------------------------------------------------------------------------
__global__ __launch_bounds__(256) void gemm2_fin_kernel(
    const unsigned short* __restrict__ xoutb, const unsigned short* __restrict__ xb,
    const short* __restrict__ WoT,
    const float* __restrict__ bt, const float* __restrict__ bskip,
    const float* __restrict__ scalpart, const float* __restrict__ wur,
    float* __restrict__ out)
{
    if (blockIdx.x == NG2) {
        __shared__ float wsum[4];
        float v = 0.0f;
        for (int i = threadIdx.x; i < NPART; i += 256) v += scalpart[i];
        #pragma unroll
        for (int off = 32; off > 0; off >>= 1) v += __shfl_down(v, off, 64);
        if ((threadIdx.x & 63) == 0) wsum[threadIdx.x >> 6] = v;
        __syncthreads();
        if (threadIdx.x == 0)
            out[(size_t)B_NODES * COUT] =
                (wsum[0] + wsum[1] + wsum[2] + wsum[3]) * wur[0];
        return;
    }

    __shared__ short As[2][64 * 40];
    __shared__ short Bs[2][128 * 40];
    __shared__ float bsum[128];

    const int tid  = threadIdx.x;
    const int w    = tid >> 6, l = tid & 63;
    const int row0 = (blockIdx.x >> 1) * 64;
    const int colbase = (blockIdx.x & 1) * 128;
    const int r    = tid >> 2, q = tid & 3;      // A staging
    const int bc_  = tid >> 1, bq = tid & 1;     // B staging: col, 16-k half
    const int grow = row0 + r;
    const int g16  = (l >> 4) * 8;

    if (tid < 128) bsum[tid] = bt[colbase + tid] + bskip[colbase + tid];

    f32x4 acc[4][2] = {};

    for (int kso = 0; kso < 8; ++kso) {
        #pragma unroll
        for (int h = 0; h < 2; ++h) {
            const int ks = kso * 2 + h;
            const int k0 = ks * 32;
            short8 sv = {0,0,0,0,0,0,0,0};
            if (grow < B_NODES) {
                const unsigned short* base = (ks < 8)
                    ? (xoutb + (size_t)grow * CIN + k0)
                    : (xb    + (size_t)grow * CIN + (k0 - 256));
                sv = *(const short8*)(base + q * 8);
            }
            *(short8*)&As[h][r * 40 + q * 8] = sv;

            const short8* wp = (const short8*)(WoT +
                (size_t)(colbase + bc_) * 512 + k0 + bq * 16);
            short8* bd = (short8*)&Bs[h][bc_ * 40 + bq * 16];
            bd[0] = wp[0]; bd[1] = wp[1];
        }
        __syncthreads();

        #pragma unroll
        for (int h = 0; h < 2; ++h) {
            short8 av[4], bv[2];
            #pragma unroll
            for (int m = 0; m < 4; ++m)
                av[m] = *(const short8*)&As[h][((l & 15) + 16 * m) * 40 + g16];
            #pragma unroll
            for (int n = 0; n < 2; ++n)
                bv[n] = *(const short8*)&Bs[h][((l & 15) + 16 * n + w * 32) * 40 + g16];
            #pragma unroll
            for (int m = 0; m < 4; ++m)
                #pragma unroll
                for (int n = 0; n < 2; ++n)
                    acc[m][n] = __builtin_amdgcn_mfma_f32_16x16x32_bf16(
                        av[m], bv[n], acc[m][n], 0, 0, 0);
        }
        __syncthreads();
    }

    #pragma unroll
    for (int m = 0; m < 4; ++m) {
        int rbase = row0 + 16 * m + (l >> 4) * 4;
        #pragma unroll
        for (int n = 0; n < 2; ++n) {
            int lcol = w * 32 + 16 * n + (l & 15);
            int col  = colbase + lcol;
            float bc = bsum[lcol];
            #pragma unroll
            for (int j = 0; j < 4; ++j) {
                int rr = rbase + j;
                if (rr < B_NODES)
                    out[(size_t)rr * COUT + col] = acc[m][n][j] + bc;
            }
        }
    }
}

// ---------------------------------------------------------------------------
extern "C" void kernel_launch(void* const* d_in, const int* in_sizes, int n_in,
                              void* d_out, int out_size, void* d_ws, size_t ws_size,
                              hipStream_t stream)
{
    const float* x       = (const float*)d_in[0];
    const float* ew      = (const float*)d_in[1];
    const float* cb      = (const float*)d_in[2];
    const float* W_conv  = (const float*)d_in[3];
    const float* b_conv  = (const float*)d_in[4];
    const float* W_t     = (const float*)d_in[5];
    const float* b_t     = (const float*)d_in[6];
    const float* W_skip  = (const float*)d_in[7];
    const float* b_skip  = (const float*)d_in[8];
    const float* wur     = (const float*)d_in[9];
    const int*   cind    = (const int*)d_in[10];
    const int*   fo      = (const int*)d_in[11];
    const int*   ei      = (const int*)d_in[12];

    float* out = (float*)d_out;

    // workspace layout (cnt & scalpart adjacent, zeroed by prepw)
    unsigned short* xwb   = (unsigned short*)d_ws;              // NTOT*CIN bf16 (51.2MB)
    unsigned short* xoutb = xwb + (size_t)NTOT * CIN;           // B*CIN bf16 (10.2MB)
    unsigned short* xb    = xoutb + (size_t)B_NODES * CIN;      // B*CIN bf16 (10.2MB)
    short* WcT      = (short*)(xb + (size_t)B_NODES * CIN);     // 256*256 bf16
    short* WoT      = WcT + 256 * 256;                          // 256*512 bf16
    int2*  esw      = (int2*)(WoT + 256 * 512);                 // NTOT*CAP (32MB)
    int*   cnt      = (int*)(esw + (size_t)NTOT * CAP);         // NTOT
    float* scalpart = (float*)(cnt + NTOT);                     // NPART

    // weight transpose + x->bf16 + zero cnt/scalpart (one launch)
    prepw_kernel<<<48 + NXCVT + NZB, 256, 0, stream>>>(
        W_conv, W_t, W_skip, WcT, WoT, x, xb, cnt);

    // GEMM1 (512-thread, BK=32, permuted tiles) with edge-scatter tail
    gemm1_scat_kernel<<<NG1, 512, 0, stream>>>(
        xb, fo, cind, cb, WcT, xwb, ei, ew, cnt, esw);

    // per-destination gather + accumulate (+ fused info_backward)
    gather_accum_kernel<<<NTOT / 4, 256, 0, stream>>>(
        xwb, esw, cnt, b_conv, fo, cind, cb, xoutb, scalpart);

    // GEMM2 (N-split, 626 blocks) + finalize
    gemm2_fin_kernel<<<NG2 + 1, 256, 0, stream>>>(
        xoutb, xb, WoT, b_t, b_skip, scalpart, wur, out);
}